// Round 1
// baseline (517.512 us; speedup 1.0000x reference)
//
#include <hip/hip_runtime.h>
#include <hip/hip_bf16.h>
#include <stdint.h>

// Problem: h_t = Lam @ h_{t-1} + B @ x_t ; BS=16, T=4096, D=256, fp32 in/out.
// Chunked scan: c=64 steps/chunk, C=64 chunks, 1024 (batch,chunk) states.

#define CHUNK  64
#define NCHUNK 64

typedef short v8s __attribute__((ext_vector_type(8)));   // 8 x bf16 (4 VGPRs)
typedef float v4f __attribute__((ext_vector_type(4)));   // MFMA accum

static __device__ __forceinline__ unsigned short f2u(float f) {
  union { float f; unsigned int u; } x; x.f = f;
  unsigned int u = x.u + 0x7FFFu + ((x.u >> 16) & 1u);   // RNE f32->bf16
  return (unsigned short)(u >> 16);
}
static __device__ __forceinline__ float u2f(unsigned short h) {
  union { unsigned int u; float f; } x; x.u = ((unsigned int)h) << 16;
  return x.f;
}

// ---------------------------------------------------------------------------
// Generic 64x64-tile bf16 MFMA GEMM. A: f32 or bf16 row-major [M,K] (lda).
// B: bf16 row-major [K,N] (ldb). C: f32 or bf16 [M,N] (ldc).
// blockIdx = (n_tile, m_tile, k_split). Per-split K length = Kper.
// Split partials go to C + z*csplit (f32 path only).
// ---------------------------------------------------------------------------
template<bool A_F32, bool C_BF16>
__global__ __launch_bounds__(256) void gemm_tile(
    const void* __restrict__ Ap, const unsigned short* __restrict__ Bp,
    void* __restrict__ Cp, int lda, int ldb, int ldc, int Kper, long csplit)
{
  __shared__ unsigned short As[64][72];   // [m][k], pad to kill bank conflicts
  __shared__ unsigned short Bst[64][72];  // [n][k] (transposed for b128 frag reads)
  const int tid = threadIdx.x;
  const int lane = tid & 63, w = tid >> 6;       // 4 waves
  const int q = lane >> 4, ln = lane & 15;
  const long n0 = (long)blockIdx.x * 64;
  const long m0 = (long)blockIdx.y * 64;
  const int  kz = blockIdx.z;
  const long kbase = (long)kz * Kper;
  const int sm = tid >> 2;          // staging row 0..63
  const int sk = (tid & 3) << 4;    // staging col 0,16,32,48

  v4f acc[4];
#pragma unroll
  for (int i = 0; i < 4; ++i) acc[i] = 0;

  for (int ks = 0; ks < Kper; ks += 64) {
    const long kg = kbase + ks;
    __syncthreads();
    if (A_F32) {
      const float* A = (const float*)Ap + (m0 + sm) * (long)lda + kg + sk;
      float4 f[4];
#pragma unroll
      for (int t = 0; t < 4; ++t) f[t] = ((const float4*)A)[t];
      unsigned short* d = &As[sm][sk];
#pragma unroll
      for (int t = 0; t < 4; ++t) {
        d[4*t+0] = f2u(f[t].x); d[4*t+1] = f2u(f[t].y);
        d[4*t+2] = f2u(f[t].z); d[4*t+3] = f2u(f[t].w);
      }
    } else {
      const unsigned short* A = (const unsigned short*)Ap + (m0 + sm) * (long)lda + kg + sk;
      v8s t0 = ((const v8s*)A)[0], t1 = ((const v8s*)A)[1];
      *(v8s*)&As[sm][sk] = t0; *(v8s*)&As[sm][sk + 8] = t1;
    }
    // stage B (transpose into [n][k])
    {
      const unsigned short* Bg = Bp + (kg + sm) * (long)ldb + n0 + sk;
      v8s b0 = ((const v8s*)Bg)[0], b1 = ((const v8s*)Bg)[1];
#pragma unroll
      for (int r = 0; r < 8; ++r) Bst[sk + r][sm] = (unsigned short)b0[r];
#pragma unroll
      for (int r = 0; r < 8; ++r) Bst[sk + 8 + r][sm] = (unsigned short)b1[r];
    }
    __syncthreads();
#pragma unroll
    for (int kb = 0; kb < 64; kb += 32) {
      v8s a = *(const v8s*)&As[w*16 + ln][kb + q*8];
#pragma unroll
      for (int nb = 0; nb < 4; ++nb) {
        v8s b = *(const v8s*)&Bst[nb*16 + ln][kb + q*8];
        acc[nb] = __builtin_amdgcn_mfma_f32_16x16x32_bf16(a, b, acc[nb], 0, 0, 0);
      }
    }
  }
#pragma unroll
  for (int nb = 0; nb < 4; ++nb)
#pragma unroll
    for (int r = 0; r < 4; ++r) {
      const long row = m0 + w*16 + q*4 + r;        // D row = 4q+r within wave's 16
      const long col = n0 + nb*16 + ln;
      float v = acc[nb][r];
      if (C_BF16) ((unsigned short*)Cp)[row * (long)ldc + col] = f2u(v);
      else        ((float*)Cp + (long)kz * csplit)[row * (long)ldc + col] = v;
    }
}

// ---------------------------------------------------------------------------
// Powers of Lam via doubling, split-bf16 (hi+lo): P_{mpow+jj} = P_mpow * P_jj,
// jj=1..mpow.  acc = Ah*Bh + Al*Bh + Ah*Bl  (drops lo*lo ~2^-18) -> ~fp32.
// ---------------------------------------------------------------------------
__global__ __launch_bounds__(256) void pow_round(
    unsigned short* __restrict__ Phi, unsigned short* __restrict__ Plo, int mpow)
{
  __shared__ unsigned short As[64][72];
  __shared__ unsigned short Bst[64][72];
  const int tid = threadIdx.x, lane = tid & 63, w = tid >> 6;
  const int q = lane >> 4, ln = lane & 15;
  const int jj = (blockIdx.x >> 2) + 1;
  const int n0 = (blockIdx.x & 3) * 64;
  const int m0 = blockIdx.y * 64;
  const unsigned short* Ah = Phi + (size_t)mpow * 65536;
  const unsigned short* Al = Plo + (size_t)mpow * 65536;
  const unsigned short* Bh = Phi + (size_t)jj * 65536;
  const unsigned short* Bl = Plo + (size_t)jj * 65536;
  const int sm = tid >> 2, sk = (tid & 3) << 4;
  v4f acc[4];
#pragma unroll
  for (int i = 0; i < 4; ++i) acc[i] = 0;

  for (int seg = 0; seg < 3; ++seg) {
    const unsigned short* Asrc = (seg == 1) ? Al : Ah;
    const unsigned short* Bsrc = (seg == 2) ? Bl : Bh;
    for (int ks = 0; ks < 256; ks += 64) {
      __syncthreads();
      {
        const unsigned short* Ag = Asrc + (size_t)(m0 + sm) * 256 + ks + sk;
        v8s t0 = ((const v8s*)Ag)[0], t1 = ((const v8s*)Ag)[1];
        *(v8s*)&As[sm][sk] = t0; *(v8s*)&As[sm][sk + 8] = t1;
      }
      {
        const unsigned short* Bg = Bsrc + (size_t)(ks + sm) * 256 + n0 + sk;
        v8s b0 = ((const v8s*)Bg)[0], b1 = ((const v8s*)Bg)[1];
#pragma unroll
        for (int r = 0; r < 8; ++r) Bst[sk + r][sm] = (unsigned short)b0[r];
#pragma unroll
        for (int r = 0; r < 8; ++r) Bst[sk + 8 + r][sm] = (unsigned short)b1[r];
      }
      __syncthreads();
#pragma unroll
      for (int kb = 0; kb < 64; kb += 32) {
        v8s a = *(const v8s*)&As[w*16 + ln][kb + q*8];
#pragma unroll
        for (int nb = 0; nb < 4; ++nb) {
          v8s bb = *(const v8s*)&Bst[nb*16 + ln][kb + q*8];
          acc[nb] = __builtin_amdgcn_mfma_f32_16x16x32_bf16(a, bb, acc[nb], 0, 0, 0);
        }
      }
    }
  }
  const size_t ob = (size_t)(mpow + jj) * 65536;
#pragma unroll
  for (int nb = 0; nb < 4; ++nb)
#pragma unroll
    for (int r = 0; r < 4; ++r) {
      const int row = m0 + w*16 + q*4 + r;
      const int col = n0 + nb*16 + ln;
      float v = acc[nb][r];
      unsigned short hi = f2u(v);
      Phi[ob + (size_t)row*256 + col] = hi;
      Plo[ob + (size_t)row*256 + col] = f2u(v - u2f(hi));
    }
}

// ---------------------------------------------------------------------------
// pack_init: Bt[e][d]=B[d][e], LamT[e][d]=Lam[d][e] (bf16); P_0=I, P_1=Lam hi/lo.
// ---------------------------------------------------------------------------
__global__ __launch_bounds__(256) void pack_init(
    const float* __restrict__ Bm, const float* __restrict__ Lam,
    unsigned short* __restrict__ Bt, unsigned short* __restrict__ LamT,
    unsigned short* __restrict__ Phi, unsigned short* __restrict__ Plo)
{
  const int idx = blockIdx.x * 256 + threadIdx.x;  // 0..65535
  const int e = idx >> 8, d = idx & 255;
  Bt[idx]   = f2u(Bm[d * 256 + e]);
  LamT[idx] = f2u(Lam[d * 256 + e]);
  float v = Lam[idx];                              // idx as (dd,ee) row-major
  unsigned short hi = f2u(v);
  Phi[65536 + idx] = hi;
  Plo[65536 + idx] = f2u(v - u2f(hi));
  const int dd = idx >> 8, ee = idx & 255;
  Phi[idx] = (dd == ee) ? (unsigned short)0x3F80 : (unsigned short)0;
  Plo[idx] = 0;
}

// ---------------------------------------------------------------------------
// pack_g: build Ghat[(j*256+e)][d] = P_{63-j}[d][e]  (summary GEMM B-operand),
//         Q[e][(j*256+d)]          = P_{j+1}[d][e]  (carry GEMM B-operand),
//         LcThi/LcTlo[e][d]        = P_64 hi/lo transposed. 64x64 LDS tiles.
// ---------------------------------------------------------------------------
__global__ __launch_bounds__(256) void pack_g(
    const unsigned short* __restrict__ Phi, const unsigned short* __restrict__ Plo,
    unsigned short* __restrict__ Ghat, unsigned short* __restrict__ Q,
    unsigned short* __restrict__ LcThi, unsigned short* __restrict__ LcTlo)
{
  __shared__ unsigned short tile[64][65];
  const int tx = threadIdx.x & 63, ty = threadIdx.x >> 6;  // ty 0..3
  const int blk = blockIdx.x;
  int t16, jpar;
  const unsigned short* src;
  if (blk < 1024)      { jpar = blk >> 4;        t16 = blk & 15;        src = Phi + (size_t)(63 - jpar) * 65536; }
  else if (blk < 2048) { int v = blk - 1024; jpar = v >> 4; t16 = v & 15; src = Phi + (size_t)(jpar + 1) * 65536; }
  else                 { jpar = 0;               t16 = blk - 2048;      src = Phi + (size_t)64 * 65536; }
  const int d0 = (t16 & 3) * 64, e0 = (t16 >> 2) * 64;

#pragma unroll
  for (int s = 0; s < 16; ++s)
    tile[ty*16 + s][tx] = src[(size_t)(d0 + ty*16 + s) * 256 + e0 + tx];
  __syncthreads();
  if (blk < 1024) {
#pragma unroll
    for (int s = 0; s < 16; ++s) {
      const int e = e0 + ty*16 + s, d = d0 + tx;
      Ghat[((size_t)(jpar*256 + e)) * 256 + d] = tile[tx][ty*16 + s];
    }
  } else if (blk < 2048) {
#pragma unroll
    for (int s = 0; s < 16; ++s) {
      const int e = e0 + ty*16 + s, d = d0 + tx;
      Q[(size_t)e * 16384 + jpar*256 + d] = tile[tx][ty*16 + s];
    }
  } else {
#pragma unroll
    for (int s = 0; s < 16; ++s)
      LcThi[(size_t)(e0 + ty*16 + s) * 256 + d0 + tx] = tile[tx][ty*16 + s];
    __syncthreads();
#pragma unroll
    for (int s = 0; s < 16; ++s)
      tile[ty*16 + s][tx] = Plo[(size_t)64*65536 + (size_t)(d0 + ty*16 + s) * 256 + e0 + tx];
    __syncthreads();
#pragma unroll
    for (int s = 0; s < 16; ++s)
      LcTlo[(size_t)(e0 + ty*16 + s) * 256 + d0 + tx] = tile[tx][ty*16 + s];
  }
}

// ---------------------------------------------------------------------------
// reduce split-K partials: S = sum_z Spart[z]
// ---------------------------------------------------------------------------
__global__ __launch_bounds__(256) void reduce_s(
    const float* __restrict__ Sp, float* __restrict__ S)
{
  const int i = blockIdx.x * 256 + threadIdx.x;   // 262144 total
  float v = 0;
#pragma unroll
  for (int z = 0; z < 8; ++z) v += Sp[(size_t)z * 262144 + i];
  S[i] = v;
}

// ---------------------------------------------------------------------------
// Phase 2: sequential chunk combine, ONE workgroup (8 waves), split-bf16 MFMA.
// H in LDS as hi/lo bf16; emits A_i (init state of chunk i) as bf16.
// ---------------------------------------------------------------------------
__global__ __launch_bounds__(512, 2) void k4_combine(
    const unsigned short* __restrict__ LcThi, const unsigned short* __restrict__ LcTlo,
    const float* __restrict__ S, unsigned short* __restrict__ Abf)
{
  __shared__ unsigned short Hhi[16][264];
  __shared__ unsigned short Hlo[16][264];
  const int tid = threadIdx.x, lane = tid & 63, w = tid >> 6;  // 8 waves
  const int q = lane >> 4, ln = lane & 15;

  v8s bhi[8][2], blo[8][2];                       // Lam^c^T frags, cols [32w,32w+32)
#pragma unroll
  for (int kk = 0; kk < 8; ++kk)
#pragma unroll
    for (int nb = 0; nb < 2; ++nb) {
      const int n = 32*w + nb*16 + ln;
#pragma unroll
      for (int r = 0; r < 8; ++r) {
        const int k = kk*32 + q*8 + r;
        bhi[kk][nb][r] = (short)LcThi[k*256 + n];
        blo[kk][nb][r] = (short)LcTlo[k*256 + n];
      }
    }
  for (int e = tid; e < 16*264; e += 512) { (&Hhi[0][0])[e] = 0; (&Hlo[0][0])[e] = 0; }
  __syncthreads();

  for (int i = 0; i < NCHUNK; ++i) {
    // A_i = state BEFORE absorbing chunk i
    for (int e = tid; e < 4096; e += 512) {
      const int b = e >> 8, d = e & 255;
      Abf[((size_t)(b*64 + i)) * 256 + d] = Hhi[b][d];
    }
    v8s ahi[8], alo[8];
#pragma unroll
    for (int kk = 0; kk < 8; ++kk) {
      ahi[kk] = *(const v8s*)&Hhi[ln][kk*32 + q*8];
      alo[kk] = *(const v8s*)&Hlo[ln][kk*32 + q*8];
    }
    __syncthreads();
    v4f acc[2];
#pragma unroll
    for (int nb = 0; nb < 2; ++nb)
#pragma unroll
      for (int r = 0; r < 4; ++r) {
        const int bb = 4*q + r, col = 32*w + nb*16 + ln;
        acc[nb][r] = S[((size_t)(bb*64 + i)) * 256 + col];
      }
#pragma unroll
    for (int kk = 0; kk < 8; ++kk)
#pragma unroll
      for (int nb = 0; nb < 2; ++nb) {
        acc[nb] = __builtin_amdgcn_mfma_f32_16x16x32_bf16(ahi[kk], bhi[kk][nb], acc[nb], 0, 0, 0);
        acc[nb] = __builtin_amdgcn_mfma_f32_16x16x32_bf16(alo[kk], bhi[kk][nb], acc[nb], 0, 0, 0);
        acc[nb] = __builtin_amdgcn_mfma_f32_16x16x32_bf16(ahi[kk], blo[kk][nb], acc[nb], 0, 0, 0);
      }
#pragma unroll
    for (int nb = 0; nb < 2; ++nb)
#pragma unroll
      for (int r = 0; r < 4; ++r) {
        const int bb = 4*q + r, col = 32*w + nb*16 + ln;
        float v = acc[nb][r];
        unsigned short hi = f2u(v);
        Hhi[bb][col] = hi;
        Hlo[bb][col] = f2u(v - u2f(hi));
      }
    __syncthreads();
  }
}

// ---------------------------------------------------------------------------
// Phase 3: local scan (init 0) + RMW-add into Out (which holds the carry from
// the K5a GEMM). 256 blocks x 4 states, 64 bf16-MFMA steps each.
// ---------------------------------------------------------------------------
__global__ __launch_bounds__(256, 1) void k5_scan(
    const unsigned short* __restrict__ LamT,
    const unsigned short* __restrict__ Bx, float* __restrict__ Out)
{
  __shared__ unsigned short gs[16][264];
  const int tid = threadIdx.x, lane = tid & 63, w = tid >> 6;  // 4 waves
  const int q = lane >> 4, ln = lane & 15;
  const int blk = blockIdx.x;
  const int b  = blk >> 4;            // batch
  const int i0 = (blk * 4) & 63;      // first chunk index of this block

  v8s bf[8][4];                        // Lam^T frags, cols [64w,64w+64)
#pragma unroll
  for (int kk = 0; kk < 8; ++kk)
#pragma unroll
    for (int nb = 0; nb < 4; ++nb) {
      const int n = 64*w + nb*16 + ln;
#pragma unroll
      for (int r = 0; r < 8; ++r)
        bf[kk][nb][r] = (short)LamT[(kk*32 + q*8 + r) * 256 + n];
    }
  for (int e = tid; e < 16*264; e += 256) (&gs[0][0])[e] = 0;
  __syncthreads();

  for (int j = 0; j < CHUNK; ++j) {
    v8s a[8];
#pragma unroll
    for (int kk = 0; kk < 8; ++kk) a[kk] = *(const v8s*)&gs[ln][kk*32 + q*8];
    __syncthreads();
    float carry[4][4], bxv[4][4];
    if (q == 0) {
#pragma unroll
      for (int r = 0; r < 4; ++r) {
        const size_t base = ((size_t)b*4096 + (size_t)(i0 + r)*64 + j) * 256;
#pragma unroll
        for (int nb = 0; nb < 4; ++nb) {
          const int col = 64*w + nb*16 + ln;
          carry[r][nb] = Out[base + col];
          bxv[r][nb]   = u2f(Bx[base + col]);
        }
      }
    }
    v4f acc[4];
#pragma unroll
    for (int nb = 0; nb < 4; ++nb) acc[nb] = 0;
#pragma unroll
    for (int kk = 0; kk < 8; ++kk)
#pragma unroll
      for (int nb = 0; nb < 4; ++nb)
        acc[nb] = __builtin_amdgcn_mfma_f32_16x16x32_bf16(a[kk], bf[kk][nb], acc[nb], 0, 0, 0);
    if (q == 0) {
#pragma unroll
      for (int r = 0; r < 4; ++r) {
        const size_t base = ((size_t)b*4096 + (size_t)(i0 + r)*64 + j) * 256;
#pragma unroll
        for (int nb = 0; nb < 4; ++nb) {
          const int col = 64*w + nb*16 + ln;
          const float g = acc[nb][r] + bxv[r][nb];
          Out[base + col] = carry[r][nb] + g;
          gs[r][col] = f2u(g);
        }
      }
    }
    __syncthreads();
  }
}

// ---------------------------------------------------------------------------
extern "C" void kernel_launch(void* const* d_in, const int* in_sizes, int n_in,
                              void* d_out, int out_size, void* d_ws, size_t ws_size,
                              hipStream_t stream)
{
  const float* x   = (const float*)d_in[0];
  const float* Bm  = (const float*)d_in[1];
  const float* Lam = (const float*)d_in[2];
  float* Out = (float*)d_out;
  (void)in_sizes; (void)n_in; (void)out_size; (void)ws_size;

  char* ws = (char*)d_ws;
  size_t off = 0;
  auto alloc = [&](size_t bytes) { void* p = ws + off; off += (bytes + 255) & ~(size_t)255; return p; };
  unsigned short* Bx    = (unsigned short*)alloc((size_t)16777216 * 2);  // 32 MB
  unsigned short* Phi   = (unsigned short*)alloc((size_t)65 * 65536 * 2);
  unsigned short* Plo   = (unsigned short*)alloc((size_t)65 * 65536 * 2);
  unsigned short* Ghat  = (unsigned short*)alloc((size_t)16384 * 256 * 2);
  unsigned short* Q     = (unsigned short*)alloc((size_t)256 * 16384 * 2);
  unsigned short* Bt    = (unsigned short*)alloc(131072);
  unsigned short* LamT  = (unsigned short*)alloc(131072);
  unsigned short* LcThi = (unsigned short*)alloc(131072);
  unsigned short* LcTlo = (unsigned short*)alloc(131072);
  float*          S     = (float*)alloc(1048576);
  unsigned short* Abf   = (unsigned short*)alloc(524288);
  float*          Spart = (float*)Plo;  // alias: Plo dead before K3 writes Spart

  // 1) packs + P0/P1
  pack_init<<<dim3(256), dim3(256), 0, stream>>>(Bm, Lam, Bt, LamT, Phi, Plo);
  // 2) Bx = x @ B^T  (bf16 out)
  gemm_tile<true, true><<<dim3(4, 1024, 1), dim3(256), 0, stream>>>(
      (const void*)x, Bt, (void*)Bx, 256, 256, 256, 256, 0);
  // 3) powers P_2..P_64 by doubling
  for (int mp = 1; mp <= 32; mp <<= 1)
    pow_round<<<dim3(mp * 4, 4, 1), dim3(256), 0, stream>>>(Phi, Plo, mp);
  // 4) pack Ghat / Q / Lam^c transposed hi,lo
  pack_g<<<dim3(2064), dim3(256), 0, stream>>>(Phi, Plo, Ghat, Q, LcThi, LcTlo);
  // 5) chunk summaries: S = Bx_reshaped[1024,16384] @ Ghat  (split-K=8)
  gemm_tile<false, false><<<dim3(4, 16, 8), dim3(256), 0, stream>>>(
      (const void*)Bx, Ghat, (void*)Spart, 16384, 256, 256, 2048, 262144);
  reduce_s<<<dim3(1024), dim3(256), 0, stream>>>(Spart, S);
  // 6) sequential combine -> chunk init states A_i (bf16)
  k4_combine<<<dim3(1), dim3(512), 0, stream>>>(LcThi, LcTlo, S, Abf);
  // 7) carry GEMM: Out[(b,i),(j,d)] = A @ Q   (layout == [b,t,d] exactly)
  gemm_tile<false, false><<<dim3(256, 16, 1), dim3(256), 0, stream>>>(
      (const void*)Abf, Q, (void*)Out, 256, 16384, 16384, 256, 0);
  // 8) local scans, h = local + carry, in-place on Out
  k5_scan<<<dim3(256), dim3(256), 0, stream>>>(LamT, Bx, Out);
}